// Round 1
// baseline (57.540 us; speedup 1.0000x reference)
//
#include <hip/hip_runtime.h>
#include <math.h>

#define NQ 12

__global__ __launch_bounds__(64) void quantum_layer_kernel(
    const float* __restrict__ x, const float* __restrict__ w,
    float* __restrict__ out, int B)
{
    int b = blockIdx.x * blockDim.x + threadIdx.x;
    if (b >= B) return;

    // Row load: 12 floats = 3 x float4 (rows are 48B, so 16B-aligned).
    const float4* xr = reinterpret_cast<const float4*>(x + (size_t)b * NQ);
    float4 v0 = xr[0], v1 = xr[1], v2 = xr[2];
    float xv[NQ] = {v0.x, v0.y, v0.z, v0.w,
                    v1.x, v1.y, v1.z, v1.w,
                    v2.x, v2.y, v2.z, v2.w};

    float c2[NQ], s2[NQ];
#pragma unroll
    for (int j = 0; j < NQ; ++j) {
        float t  = tanhf(xv[j]);
        float t2 = t * t;
        float inv = 1.0f / (1.0f + t2);
        c2[j] = (1.0f - t2) * inv;   // cos(2*arctan(t))
        s2[j] = 2.0f * t * inv;      // sin(2*arctan(t))
    }

    float o[NQ];
    float P = 1.0f;
#pragma unroll
    for (int q = 0; q < NQ; ++q) {
        P *= c2[q];
        float S = (q < NQ - 1) ? s2[q] * s2[q + 1] : s2[q];
        float sw, cw;
        sincosf(w[q], &sw, &cw);     // w[q] is wave-uniform -> scalarized load
        o[q] = cw * P - sw * S;
    }

    float4* orow = reinterpret_cast<float4*>(out + (size_t)b * NQ);
    orow[0] = make_float4(o[0], o[1], o[2],  o[3]);
    orow[1] = make_float4(o[4], o[5], o[6],  o[7]);
    orow[2] = make_float4(o[8], o[9], o[10], o[11]);
}

extern "C" void kernel_launch(void* const* d_in, const int* in_sizes, int n_in,
                              void* d_out, int out_size, void* d_ws, size_t ws_size,
                              hipStream_t stream) {
    const float* x = (const float*)d_in[0];
    const float* w = (const float*)d_in[1];
    float* out = (float*)d_out;
    int B = in_sizes[0] / NQ;   // 16384

    dim3 block(64);
    dim3 grid((B + block.x - 1) / block.x);   // 256 blocks -> 1 wave/CU
    hipLaunchKernelGGL(quantum_layer_kernel, grid, block, 0, stream,
                       x, w, out, B);
}

// Round 2
// 55.004 us; speedup vs baseline: 1.0461x; 1.0461x over previous
//
#include <hip/hip_runtime.h>
#include <math.h>

#define NQ 12

__global__ __launch_bounds__(64) void quantum_layer_kernel(
    const float* __restrict__ x, const float* __restrict__ w,
    float* __restrict__ out, int B)
{
    int b = blockIdx.x * blockDim.x + threadIdx.x;
    if (b >= B) return;

    // Row load: 12 floats = 3 x float4 (rows are 48B, 16B-aligned).
    const float4* xr = reinterpret_cast<const float4*>(x + (size_t)b * NQ);
    float4 v0 = xr[0], v1 = xr[1], v2 = xr[2];
    float xv[NQ] = {v0.x, v0.y, v0.z, v0.w,
                    v1.x, v1.y, v1.z, v1.w,
                    v2.x, v2.y, v2.z, v2.w};

    // Identities: cos(2*arctan(tanh x)) = sech(2x), sin(2*arctan(tanh x)) = tanh(2x).
    // With u = e^{2x}:  c2 = 2u/(u^2+1),  s2 = (u^2-1)/(u^2+1).
    float c2[NQ], s2[NQ];
#pragma unroll
    for (int j = 0; j < NQ; ++j) {
        float xc  = fminf(fmaxf(xv[j], -15.0f), 15.0f);  // avoid u^2 overflow -> NaN
        float u   = __expf(2.0f * xc);                   // native v_exp_f32
        float u2  = u * u;
        float inv = __builtin_amdgcn_rcpf(u2 + 1.0f);    // native v_rcp_f32
        c2[j] = 2.0f * u * inv;
        s2[j] = (u2 - 1.0f) * inv;
    }

    // out[q] = cos(w_q) * prod_{j<=q} c2_j  -  sin(w_q) * (s2_q * s2_{q+1} | s2_11)
    float o[NQ];
    float P = 1.0f;
#pragma unroll
    for (int q = 0; q < NQ; ++q) {
        P *= c2[q];
        float S  = (q < NQ - 1) ? s2[q] * s2[q + 1] : s2[q];
        float wq = w[q];                 // uniform -> scalar load
        float sw = __sinf(wq);           // native v_sin_f32 (|w| ~ 0.01, no reduction needed)
        float cw = __cosf(wq);
        o[q] = cw * P - sw * S;
    }

    float4* orow = reinterpret_cast<float4*>(out + (size_t)b * NQ);
    orow[0] = make_float4(o[0], o[1], o[2],  o[3]);
    orow[1] = make_float4(o[4], o[5], o[6],  o[7]);
    orow[2] = make_float4(o[8], o[9], o[10], o[11]);
}

extern "C" void kernel_launch(void* const* d_in, const int* in_sizes, int n_in,
                              void* d_out, int out_size, void* d_ws, size_t ws_size,
                              hipStream_t stream) {
    const float* x = (const float*)d_in[0];
    const float* w = (const float*)d_in[1];
    float* out = (float*)d_out;
    int B = in_sizes[0] / NQ;   // 16384

    dim3 block(64);
    dim3 grid((B + block.x - 1) / block.x);   // 256 blocks -> 1 wave/CU
    hipLaunchKernelGGL(quantum_layer_kernel, grid, block, 0, stream,
                       x, w, out, B);
}